// Round 16
// baseline (73.419 us; speedup 1.0000x reference)
//
#include <hip/hip_runtime.h>
#include <math.h>

typedef __attribute__((ext_vector_type(8))) short bf16x8;
typedef __attribute__((ext_vector_type(4))) short bf16x4;
typedef __attribute__((ext_vector_type(4))) float f32x4;
typedef __attribute__((ext_vector_type(16))) float f32x16;

#define BB    4
#define SEQ   1024
#define DIMV  512
#define TD    1536
#define NH    8
#define DH    128
#define MROWS (BB*SEQ)

__device__ inline unsigned short f2bf(float x){
    union { float f; unsigned u; } v; v.f = x;
    unsigned r = v.u + 0x7FFF + ((v.u >> 16) & 1);   // RNE
    return (unsigned short)(r >> 16);
}
__device__ inline float bf2f(unsigned short h){
    union { unsigned u; float f; } v; v.u = ((unsigned)h) << 16; return v.f;
}

__device__ inline void glds16(const void* g, void* l){
    __builtin_amdgcn_global_load_lds(
        (const __attribute__((address_space(1))) unsigned int*)g,
        (__attribute__((address_space(3))) unsigned int*)l,
        16, 0, 0);
}

// ---------------- Prep A: x|a -> bf16, K-granule-major (thin copy, low VGPR) --------
__global__ __launch_bounds__(256) void prep_a(
    const float* __restrict__ X, const float* __restrict__ A,
    unsigned short* __restrict__ Ab)
{
    const int m   = blockIdx.x*256 + threadIdx.x;
    const int pg  = blockIdx.y;         // p*4+g  (0..63)
    const int mat = blockIdx.z;
    const float* In = mat ? A : X;
    const float* src = In + (size_t)m*DIMV + pg*8;
    float4 v0 = *(const float4*)src;
    float4 v1 = *(const float4*)(src+4);
    float v[8] = {v0.x,v0.y,v0.z,v0.w,v1.x,v1.y,v1.z,v1.w};
    bf16x8 h;
    #pragma unroll
    for (int j=0;j<8;++j) h[j] = (short)f2bf(v[j]);
    const size_t o = ((size_t)(mat*64 + pg)*4096 + m)*8;
    *(bf16x8*)(Ab+o) = h;
}

// ------- Prep B: transpose W -> bf16 K-granule-major (x-block 6 builds RoPE table) ---
__global__ __launch_bounds__(256) void prep_b(
    const float* __restrict__ Wx, const float* __restrict__ Wa,
    unsigned short* __restrict__ Bhi,
    float2* __restrict__ tab)
{
    if (blockIdx.x == 6){
        const int i = (blockIdx.z*64 + blockIdx.y)*256 + threadIdx.x;   // 0..32767
        #pragma unroll
        for (int k=0;k<2;++k){
            const int idx = i + k*32768;
            const int n = idx >> 6, dd = idx & 63;
            const float inv = expf((float)dd * (1.f/64.f) * -9.210340371976184f);
            const float ang = (float)n * inv;
            float sn, cs;
            sincosf(ang, &sn, &cs);
            tab[idx] = make_float2(cs, sn);
        }
        return;
    }
    const int n   = blockIdx.x*256 + threadIdx.x;
    const int pg  = blockIdx.y;
    const int mat = blockIdx.z;
    const float* W = mat ? Wa : Wx;
    bf16x8 h;
    #pragma unroll
    for (int j=0;j<8;++j)
        h[j] = (short)f2bf(W[(size_t)(pg*8 + j)*TD + n]);
    const size_t o = ((size_t)(mat*64 + pg)*1536 + n)*8;
    *(bf16x8*)(Bhi+o) = h;
}

// ---------------- Kernel 1: QKV GEMM via bf16 MFMA, BK=64, 1-pass bf16 W -------------
__global__ __launch_bounds__(256,3) void qkv_mfma(
    const unsigned short* __restrict__ Ab,
    const unsigned short* __restrict__ Bhi,
    unsigned short* __restrict__ wsqb, unsigned short* __restrict__ wskb,
    unsigned short* __restrict__ Vf)
{
    __shared__ __align__(16) unsigned short sA [8192];
    __shared__ __align__(16) unsigned short sBh[8192];

    const int mat = blockIdx.z;
    const int bm  = blockIdx.x * 128;
    const int bn  = blockIdx.y * 128;
    const bool vblk = (bn >= 1024);
    const int tid = threadIdx.x;
    const int w   = tid >> 6, l = tid & 63;
    const int wr  = w >> 1,  wc = w & 1;
    const int lg  = l >> 4,  ln = l & 15;

    f32x4 acc[4][4];
    #pragma unroll
    for (int i=0;i<4;++i)
        #pragma unroll
        for (int j=0;j<4;++j){ acc[i][j][0]=0.f; acc[i][j][1]=0.f; acc[i][j][2]=0.f; acc[i][j][3]=0.f; }

    const int g0 = tid >> 7, r0 = tid & 127;
    const size_t ASTEP = (size_t)8*4096*8;     // 8 granule-panels per K-step
    const size_t BSTEP = (size_t)8*1536*8;
    const unsigned short* aP  = Ab  + ((size_t)(mat*64 + g0)*4096 + bm + r0)*8;
    const unsigned short* bPh = Bhi + ((size_t)(mat*64 + g0)*1536 + bn + r0)*8;
    const size_t AC = (size_t)2*4096*8;        // per-c offset (2 panels)
    const size_t BC = (size_t)2*1536*8;

    for (int p=0; p<8; ++p){
        #pragma unroll
        for (int c=0;c<4;++c){
            glds16(aP  + c*AC, sA  + (c*256+tid)*8);
            glds16(bPh + c*BC, sBh + (c*256+tid)*8);
        }
        aP += ASTEP; bPh += BSTEP;
        __syncthreads();

        #pragma unroll
        for (int kk=0;kk<2;++kk){
            bf16x8 av[4], bh[4];
            #pragma unroll
            for (int mi=0; mi<4; ++mi){
                const int off = ((kk*4+lg)*128 + wr*64 + mi*16 + ln)*8;
                av[mi] = *(const bf16x8*)(sA + off);
            }
            #pragma unroll
            for (int ni=0; ni<4; ++ni){
                const int off = ((kk*4+lg)*128 + wc*64 + ni*16 + ln)*8;
                bh[ni] = *(const bf16x8*)(sBh + off);
            }
            #pragma unroll
            for (int mi=0; mi<4; ++mi)
                #pragma unroll
                for (int ni=0; ni<4; ++ni)
                    acc[mi][ni] = __builtin_amdgcn_mfma_f32_16x16x32_bf16(av[mi], bh[ni], acc[mi][ni], 0,0,0);
        }
        __syncthreads();
    }

    const int b_ = bm >> 10;
    const int n0base = (bm & 1023) + wr*64;
    const int colB = bn + wc*64;
    if (!vblk){
        unsigned short* base = (colB < 512) ? wsqb : wskb;
        #pragma unroll
        for (int ni=0; ni<4; ++ni){
            const int col = colB + ni*16 + ln;
            const int h = mat*4 + ((col >> 7) & 3);
            const int d = col & 127;
            #pragma unroll
            for (int mi=0; mi<4; ++mi){
                const int n0 = n0base + mi*16 + lg*4;
                unsigned short* dst = base + ((size_t)(b_*NH + h)*SEQ + n0)*DH + d;
                #pragma unroll
                for (int r=0;r<4;++r) dst[r*DH] = f2bf(acc[mi][ni][r]);
            }
        }
    } else {
        // V -> fragment-major: Vf[((bh*32+kt)*2+kc)*4+dt][lane][8]
        #pragma unroll
        for (int ni=0; ni<4; ++ni){
            const int col = colB + ni*16 + ln;
            const int h  = mat*4 + ((col >> 7) & 3);
            const int d  = col & 127;
            const int dt = d >> 5;
            const int lane = (d & 31) + 32*(lg >> 1);
            const int bh = b_*NH + h;
            #pragma unroll
            for (int mi=0; mi<4; ++mi){
                const int kt = (n0base + mi*16) >> 5;
                const int kc = mi & 1;
                unsigned short* dst = Vf +
                    ((((size_t)(bh*32 + kt)*2 + kc)*4 + dt)*64 + lane)*8 + (lg&1)*4;
                bf16x4 pk;
                #pragma unroll
                for (int r=0;r<4;++r) pk[r] = (short)f2bf(acc[mi][ni][r]);
                *(bf16x4*)dst = pk;
            }
        }
    }
}

// ---------------- Kernel 2: LayerNorm + RoPE, wave-per-row (no LDS/barriers) --------
__global__ __launch_bounds__(256) void ln_rope(
    const unsigned short* __restrict__ wsqb, const unsigned short* __restrict__ wskb,
    unsigned short* __restrict__ Qb, unsigned short* __restrict__ Kb,
    const float2* __restrict__ tab,
    const float* __restrict__ g_qx, const float* __restrict__ b_qx,
    const float* __restrict__ g_kx, const float* __restrict__ b_kx,
    const float* __restrict__ g_qa, const float* __restrict__ b_qa,
    const float* __restrict__ g_ka, const float* __restrict__ b_ka)
{
    const int w0   = threadIdx.x >> 6;
    const int lane = threadIdx.x & 63;
    const int inst = blockIdx.x*4 + w0;        // 0..16383
    const int which = inst & 3;
    const int r = inst >> 2;
    const int b_ = r >> 10, n_ = r & 1023;

    const unsigned short* buf = (which & 1) ? wskb : wsqb;
    unsigned short* ob = (which & 1) ? Kb : Qb;
    const int h0 = (which >> 1) ? 4 : 0;
    const float* g; const float* bb;
    if (which==0){ g=g_qx; bb=b_qx; }
    else if (which==1){ g=g_kx; bb=b_kx; }
    else if (which==2){ g=g_qa; bb=b_qa; }
    else { g=g_ka; bb=b_ka; }

    const int hc = lane >> 4;
    const int h  = h0 + hc;
    const int d0 = (lane & 15) * 8;
    const size_t idx = ((size_t)(b_*NH + h)*SEQ + n_)*DH + d0;

    bf16x8 vin = *(const bf16x8*)(buf + idx);
    float v[8];
    float s1 = 0.f, s2 = 0.f;
    #pragma unroll
    for (int j=0;j<8;++j){
        v[j] = bf2f((unsigned short)vin[j]);
        s1 += v[j]; s2 += v[j]*v[j];
    }
    #pragma unroll
    for (int off=1; off<64; off<<=1){
        s1 += __shfl_xor(s1, off);
        s2 += __shfl_xor(s2, off);
    }
    const float mu = s1 * (1.f/512.f);
    const float var = s2 * (1.f/512.f) - mu*mu;
    const float rs = rsqrtf(var + 1e-5f);

    const int e = lane*8;
    float4 gv0 = *(const float4*)(g + e);
    float4 gv1 = *(const float4*)(g + e + 4);
    float4 bv0 = *(const float4*)(bb + e);
    float4 bv1 = *(const float4*)(bb + e + 4);
    const float gg[8]  = {gv0.x,gv0.y,gv0.z,gv0.w,gv1.x,gv1.y,gv1.z,gv1.w};
    const float bbv[8] = {bv0.x,bv0.y,bv0.z,bv0.w,bv1.x,bv1.y,bv1.z,bv1.w};

    float xn[8];
    #pragma unroll
    for (int j=0;j<8;++j) xn[j] = (v[j]-mu)*rs*gg[j] + bbv[j];

    float pr[8];
    #pragma unroll
    for (int j=0;j<8;++j) pr[j] = __shfl_xor(xn[j], 8);   // partner: d ^ 64 <=> lane ^ 8

    const bool firsthalf = (lane & 8) == 0;
    const float2* tp = tab + (n_ << 6) + (lane & 7)*8;
    const float qs = 0.08838834764831845f * 1.4426950408889634f;
    bf16x8 outv;
    #pragma unroll
    for (int j=0;j<8;++j){
        const float2 cs = tp[j];
        const float rot = firsthalf ? -pr[j] : pr[j];
        float val = xn[j]*cs.x + rot*cs.y;
        if (!(which & 1)) val *= qs;
        outv[j] = (short)f2bf(val);
    }
    *(bf16x8*)(ob + idx) = outv;
}

// ---------------- Kernel 3: 32x32 MFMA flash attention, QB=128, 64 keys/wave-phase ---
// 8 waves (4 qg x 2 ks), 512 threads, grid 256 = 1 block/CU (no tail). K ring: 2 slots
// x 4 tiles (64KB) via global_load_lds, staged one phase ahead, shared by all 8 waves
// (halves K L2 traffic + staging instr vs QB=64). V loaded global->reg per wave from
// fragment-major Vf. 1 barrier/128 keys-per-wave-pair.
__global__ __launch_bounds__(512,2) void attn_mfma(
    const unsigned short* __restrict__ Qb, const unsigned short* __restrict__ Kb,
    const unsigned short* __restrict__ Vf, float* __restrict__ out)
{
    __shared__ __align__(16) unsigned short SMEM[34816];   // 68KB: ring 64KB / epilogue 68.6KB

    // XCD-aware remap: 8 q-tile blocks of one bh land on one XCD
    const int nblk = blockIdx.x;            // 0..255
    const int xcd  = nblk & 7;
    const int jj   = nblk >> 3;             // 0..31
    const int bh   = xcd*4 + (jj >> 3);
    const int q0   = (jj & 7) * 128;

    const int tid = threadIdx.x;
    const int w   = tid >> 6;
    const int qg  = w >> 1;      // q-group: rows q0+qg*32 .. +31
    const int ks  = w & 1;       // K-tile parity
    const int l   = tid & 63;
    const int lq  = l & 31;      // q column / V d-column
    const int h   = l >> 5;      // k-half within fragments
    const size_t hoff = (size_t)bh * SEQ * DH;

    bf16x8 qf[8];
    {
        const unsigned short* qp = Qb + hoff + (size_t)(q0 + qg*32 + lq)*DH + h*8;
        #pragma unroll
        for (int dc=0;dc<8;++dc) qf[dc] = *(const bf16x8*)(qp + dc*16);
    }

    f32x16 o[4];
    #pragma unroll
    for (int dt=0;dt<4;++dt)
        #pragma unroll
        for (int i=0;i<16;++i) o[dt][i] = 0.f;
    float mrun = -INFINITY, lrun = 0.f;

    const unsigned short* kg0 = Kb + hoff;
    const unsigned short* vt0 = Vf + (size_t)bh*32*4096 + l*8;   // per-tile 4096 elems

    // Stage tile group grp (tiles 4*grp .. 4*grp+3) into ring slot bb (16K shorts).
    // 512 threads: one 16B granule per thread per tile.
    #define STAGE_K(bb, grp) { \
        unsigned short* base_ = SMEM + (bb)*16384; \
        const unsigned short* ks_ = kg0 + (size_t)(4*(grp))*4096; \
        _Pragma("unroll") \
        for (int t_=0;t_<4;++t_){ \
            int r_ = tid >> 4, s_ = tid & 15; \
            glds16(ks_ + t_*4096 + r_*128 + ((s_ ^ (r_&7))*8), base_ + t_*4096 + tid*8); \
        } }

    #define LOADV(VF_, tile) { \
        const unsigned short* vb_ = vt0 + (size_t)(tile)*4096; \
        _Pragma("unroll") \
        for (int kc_=0;kc_<2;++kc_) \
            _Pragma("unroll") \
            for (int dt_=0;dt_<4;++dt_) \
                VF_[kc_][dt_] = *(const bf16x8*)(vb_ + (kc_*4+dt_)*512); }

    // One 32-key sub-phase: S from LDS slot, online softmax, in-register P, PV.
    #define SUB(slot, VF_) { \
        const unsigned short* kb = SMEM + cur*16384 + (slot)*4096 + lq*128; \
        f32x16 s; \
        _Pragma("unroll") \
        for (int i=0;i<16;++i) s[i] = 0.f; \
        _Pragma("unroll") \
        for (int dc=0;dc<8;++dc){ \
            bf16x8 kf = *(const bf16x8*)(kb + (((dc*2+h) ^ (lq&7))*8)); \
            s = __builtin_amdgcn_mfma_f32_32x32x16_bf16(kf, qf[dc], s, 0,0,0); \
        } \
        float mx = fmaxf(s[0], s[1]); \
        _Pragma("unroll") \
        for (int i=2;i<16;++i) mx = fmaxf(mx, s[i]); \
        mx = fmaxf(mx, __shfl_xor(mx, 32)); \
        if (__any(mx > mrun + 8.f)){ \
            const float mn = fmaxf(mrun, mx); \
            const float al = __builtin_amdgcn_exp2f(mrun - mn); \
            mrun = mn; lrun *= al; \
            _Pragma("unroll") \
            for (int dt=0;dt<4;++dt) \
                _Pragma("unroll") \
                for (int i=0;i<16;++i) o[dt][i] *= al; \
        } \
        float su = 0.f; \
        _Pragma("unroll") \
        for (int i=0;i<16;++i){ s[i] = __builtin_amdgcn_exp2f(s[i]-mrun); su += s[i]; } \
        su += __shfl_xor(su, 32); \
        lrun += su; \
        bf16x8 pf[2]; \
        _Pragma("unroll") \
        for (int kc=0; kc<2; ++kc){ \
            const int b8 = kc*8; \
            unsigned Aq, Bq, Cq, Dq; \
            asm("v_cvt_pk_bf16_f32 %0, %1, %2" : "=v"(Aq) : "v"(s[b8+0]), "v"(s[b8+1])); \
            asm("v_cvt_pk_bf16_f32 %0, %1, %2" : "=v"(Bq) : "v"(s[b8+2]), "v"(s[b8+3])); \
            asm("v_cvt_pk_bf16_f32 %0, %1, %2" : "=v"(Cq) : "v"(s[b8+4]), "v"(s[b8+5])); \
            asm("v_cvt_pk_bf16_f32 %0, %1, %2" : "=v"(Dq) : "v"(s[b8+6]), "v"(s[b8+7])); \
            asm("v_permlane32_swap_b32 %0, %1" : "+v"(Aq), "+v"(Cq)); \
            asm("v_permlane32_swap_b32 %0, %1" : "+v"(Bq), "+v"(Dq)); \
            union { unsigned u[4]; bf16x8 v; } pk; \
            pk.u[0] = Aq; pk.u[1] = Bq; pk.u[2] = Cq; pk.u[3] = Dq; \
            pf[kc] = pk.v; \
        } \
        _Pragma("unroll") \
        for (int kc=0;kc<2;++kc) \
            _Pragma("unroll") \
            for (int dt=0;dt<4;++dt) \
                o[dt] = __builtin_amdgcn_mfma_f32_32x32x16_bf16(VF_[kc][dt], pf[kc], o[dt], 0,0,0); }

    bf16x8 vf0[2][4], vf1[2][4];

    STAGE_K(0, 0);
    __syncthreads();

    int cur = 0;
    for (int ii=0; ii<8; ++ii){
        LOADV(vf0, 4*ii + ks);
        LOADV(vf1, 4*ii + 2 + ks);
        if (ii < 7) STAGE_K(cur^1, ii+1);
        SUB(ks,     vf0);
        SUB(2 + ks, vf1);
        __syncthreads();
        cur ^= 1;
    }
    #undef SUB
    #undef STAGE_K
    #undef LOADV

    // ---- epilogue: merge parity partials per q-group, transpose, store ----
    float* Lm = (float*)SMEM;            // [4 qg][2 ks][32] running max
    float* Ll = Lm + 256;                // [4 qg][2 ks][32] running sum
    Lm[(qg*2+ks)*32 + lq] = mrun;
    Ll[(qg*2+ks)*32 + lq] = lrun;
    __syncthreads();
    const float mo  = Lm[(qg*2+(ks^1))*32 + lq];
    const float lo_ = Ll[(qg*2+(ks^1))*32 + lq];
    const float mf = fmaxf(mrun, mo);
    const float a  = __builtin_amdgcn_exp2f(mrun - mf);
    const float ao = __builtin_amdgcn_exp2f(mo - mf);
    const float lf = lrun*a + lo_*ao;
    float* Ob = (float*)SMEM + 512 + qg*4160;   // 4 panes of [32 q][stride 129] f32
    if (ks == 1){
        #pragma unroll
        for (int dt=0;dt<4;++dt)
            #pragma unroll
            for (int r=0;r<16;++r){
                const int d = dt*32 + (r&3) + 8*(r>>2) + 4*h;
                Ob[lq*129 + d] = o[dt][r]*a;
            }
    }
    __syncthreads();
    if (ks == 0){
        const float inv = 1.0f/lf;
        #pragma unroll
        for (int dt=0;dt<4;++dt)
            #pragma unroll
            for (int r=0;r<16;++r){
                const int d = dt*32 + (r&3) + 8*(r>>2) + 4*h;
                const int idx = lq*129 + d;
                Ob[idx] = (o[dt][r]*a + Ob[idx])*inv;
            }
    }
    __syncthreads();
    const int b_ = bh >> 3, h_ = bh & 7;
    const int row = tid >> 2, quarter = tid & 3;      // row 0..127
    const float* src = (const float*)SMEM + 512 + (row>>5)*4160 + (row&31)*129 + quarter*32;
    float* dst = out + ((size_t)(b_*SEQ) + q0 + row)*1024 + h_*128 + quarter*32;
    #pragma unroll
    for (int j=0;j<8;++j)
        *(float4*)(dst + j*4) = *(const float4*)(src + j*4);
}

extern "C" void kernel_launch(void* const* d_in, const int* in_sizes, int n_in,
                              void* d_out, int out_size, void* d_ws, size_t ws_size,
                              hipStream_t stream) {
    const float* x    = (const float*)d_in[0];
    const float* a    = (const float*)d_in[1];
    const float* Wx   = (const float*)d_in[2];
    const float* Wa   = (const float*)d_in[3];
    const float* g_qx = (const float*)d_in[4];
    const float* b_qx = (const float*)d_in[5];
    const float* g_kx = (const float*)d_in[6];
    const float* b_kx = (const float*)d_in[7];
    const float* g_qa = (const float*)d_in[8];
    const float* b_qa = (const float*)d_in[9];
    const float* g_ka = (const float*)d_in[10];
    const float* b_ka = (const float*)d_in[11];
    float* out = (float*)d_out;

    const size_t E = (size_t)BB*NH*SEQ*DH;        // 4,194,304 elements
    unsigned short* wsqb = (unsigned short*)d_ws; // 8MB bf16 pre-LN q
    unsigned short* wskb = wsqb + E;              // 8MB bf16 pre-LN k
    unsigned short* Vf   = wskb + E;              // 8MB fragment-major V
    unsigned short* region = Vf + E;
    unsigned short* Ab  = region;                 // 8MB (gemm phase)
    unsigned short* Qb  = region;                 // 8MB (attn phase, overlays Ab)
    unsigned short* Kb  = region + E;             // 8MB
    unsigned short* Bhi = region + 2*E;           // 3MB
    float2* tab = (float2*)(Bhi + (size_t)2*64*1536*8);  // 512KB

    prep_a<<<dim3(16, 64, 2), 256, 0, stream>>>(x, a, Ab);
    prep_b<<<dim3(7, 64, 2), 256, 0, stream>>>(Wx, Wa, Bhi, tab);
    qkv_mfma<<<dim3(32, 12, 2), 256, 0, stream>>>(Ab, Bhi, wsqb, wskb, Vf);
    ln_rope<<<dim3(4096), 256, 0, stream>>>(wsqb, wskb, Qb, Kb, tab,
        g_qx, b_qx, g_kx, b_kx, g_qa, b_qa, g_ka, b_ka);
    attn_mfma<<<dim3(256), 512, 0, stream>>>(Qb, Kb, Vf, out);
}

// Round 17
// 70.535 us; speedup vs baseline: 1.0409x; 1.0409x over previous
//
#include <hip/hip_runtime.h>
#include <math.h>

typedef __attribute__((ext_vector_type(8))) short bf16x8;
typedef __attribute__((ext_vector_type(4))) short bf16x4;
typedef __attribute__((ext_vector_type(4))) float f32x4;
typedef __attribute__((ext_vector_type(16))) float f32x16;

#define BB    4
#define SEQ   1024
#define DIMV  512
#define TD    1536
#define NH    8
#define DH    128
#define MROWS (BB*SEQ)

__device__ inline unsigned short f2bf(float x){
    union { float f; unsigned u; } v; v.f = x;
    unsigned r = v.u + 0x7FFF + ((v.u >> 16) & 1);   // RNE
    return (unsigned short)(r >> 16);
}
__device__ inline float bf2f(unsigned short h){
    union { unsigned u; float f; } v; v.u = ((unsigned)h) << 16; return v.f;
}

__device__ inline void glds16(const void* g, void* l){
    __builtin_amdgcn_global_load_lds(
        (const __attribute__((address_space(1))) unsigned int*)g,
        (__attribute__((address_space(3))) unsigned int*)l,
        16, 0, 0);
}

// ---------------- Prep A: x|a -> bf16, K-granule-major (full-line coalesced) --------
// Lane (rl,p8): reads 8-lane x 256B contiguous runs; writes 128B contiguous per pg.
__global__ __launch_bounds__(256) void prep_a(
    const float* __restrict__ X, const float* __restrict__ A,
    unsigned short* __restrict__ Ab)
{
    const int bm  = blockIdx.x * 32;     // 128 blocks x 32 rows
    const int mat = blockIdx.y;
    const float* In = mat ? A : X;
    const int t  = threadIdx.x;
    const int rl = t >> 3;               // 0..31
    const int p8 = t & 7;                // 0..7
    const int m  = bm + rl;
    #pragma unroll
    for (int g=0; g<8; ++g){
        const int pg = g*8 + p8;
        const float* src = In + (size_t)m*DIMV + pg*8;
        float4 v0 = *(const float4*)src;
        float4 v1 = *(const float4*)(src+4);
        float v[8] = {v0.x,v0.y,v0.z,v0.w,v1.x,v1.y,v1.z,v1.w};
        bf16x8 hh;
        #pragma unroll
        for (int j=0;j<8;++j) hh[j] = (short)f2bf(v[j]);
        *(bf16x8*)(Ab + ((size_t)(mat*64 + pg)*4096 + m)*8) = hh;
    }
}

// ------- Prep B: transpose W -> bf16 K-granule-major (x-block 6 builds RoPE table) ---
__global__ __launch_bounds__(256) void prep_b(
    const float* __restrict__ Wx, const float* __restrict__ Wa,
    unsigned short* __restrict__ Bhi,
    float2* __restrict__ tab)
{
    if (blockIdx.x == 6){
        const int i = (blockIdx.z*64 + blockIdx.y)*256 + threadIdx.x;   // 0..32767
        #pragma unroll
        for (int k=0;k<2;++k){
            const int idx = i + k*32768;
            const int n = idx >> 6, dd = idx & 63;
            const float inv = expf((float)dd * (1.f/64.f) * -9.210340371976184f);
            const float ang = (float)n * inv;
            float sn, cs;
            sincosf(ang, &sn, &cs);
            tab[idx] = make_float2(cs, sn);
        }
        return;
    }
    const int n   = blockIdx.x*256 + threadIdx.x;
    const int pg  = blockIdx.y;
    const int mat = blockIdx.z;
    const float* W = mat ? Wa : Wx;
    bf16x8 h;
    #pragma unroll
    for (int j=0;j<8;++j)
        h[j] = (short)f2bf(W[(size_t)(pg*8 + j)*TD + n]);
    const size_t o = ((size_t)(mat*64 + pg)*1536 + n)*8;
    *(bf16x8*)(Bhi+o) = h;
}

// ---------------- Kernel 1: QKV GEMM via bf16 MFMA, BK=64, 1-pass bf16 W -------------
__global__ __launch_bounds__(256,3) void qkv_mfma(
    const unsigned short* __restrict__ Ab,
    const unsigned short* __restrict__ Bhi,
    unsigned short* __restrict__ wsqb, unsigned short* __restrict__ wskb,
    unsigned short* __restrict__ Vf)
{
    __shared__ __align__(16) unsigned short sA [8192];
    __shared__ __align__(16) unsigned short sBh[8192];

    const int mat = blockIdx.z;
    const int bm  = blockIdx.x * 128;
    const int bn  = blockIdx.y * 128;
    const bool vblk = (bn >= 1024);
    const int tid = threadIdx.x;
    const int w   = tid >> 6, l = tid & 63;
    const int wr  = w >> 1,  wc = w & 1;
    const int lg  = l >> 4,  ln = l & 15;

    f32x4 acc[4][4];
    #pragma unroll
    for (int i=0;i<4;++i)
        #pragma unroll
        for (int j=0;j<4;++j){ acc[i][j][0]=0.f; acc[i][j][1]=0.f; acc[i][j][2]=0.f; acc[i][j][3]=0.f; }

    const int g0 = tid >> 7, r0 = tid & 127;
    const size_t ASTEP = (size_t)8*4096*8;     // 8 granule-panels per K-step
    const size_t BSTEP = (size_t)8*1536*8;
    const unsigned short* aP  = Ab  + ((size_t)(mat*64 + g0)*4096 + bm + r0)*8;
    const unsigned short* bPh = Bhi + ((size_t)(mat*64 + g0)*1536 + bn + r0)*8;
    const size_t AC = (size_t)2*4096*8;        // per-c offset (2 panels)
    const size_t BC = (size_t)2*1536*8;

    for (int p=0; p<8; ++p){
        #pragma unroll
        for (int c=0;c<4;++c){
            glds16(aP  + c*AC, sA  + (c*256+tid)*8);
            glds16(bPh + c*BC, sBh + (c*256+tid)*8);
        }
        aP += ASTEP; bPh += BSTEP;
        __syncthreads();

        #pragma unroll
        for (int kk=0;kk<2;++kk){
            bf16x8 av[4], bh[4];
            #pragma unroll
            for (int mi=0; mi<4; ++mi){
                const int off = ((kk*4+lg)*128 + wr*64 + mi*16 + ln)*8;
                av[mi] = *(const bf16x8*)(sA + off);
            }
            #pragma unroll
            for (int ni=0; ni<4; ++ni){
                const int off = ((kk*4+lg)*128 + wc*64 + ni*16 + ln)*8;
                bh[ni] = *(const bf16x8*)(sBh + off);
            }
            #pragma unroll
            for (int mi=0; mi<4; ++mi)
                #pragma unroll
                for (int ni=0; ni<4; ++ni)
                    acc[mi][ni] = __builtin_amdgcn_mfma_f32_16x16x32_bf16(av[mi], bh[ni], acc[mi][ni], 0,0,0);
        }
        __syncthreads();
    }

    const int b_ = bm >> 10;
    const int n0base = (bm & 1023) + wr*64;
    const int colB = bn + wc*64;
    if (!vblk){
        unsigned short* base = (colB < 512) ? wsqb : wskb;
        #pragma unroll
        for (int ni=0; ni<4; ++ni){
            const int col = colB + ni*16 + ln;
            const int h = mat*4 + ((col >> 7) & 3);
            const int d = col & 127;
            #pragma unroll
            for (int mi=0; mi<4; ++mi){
                const int n0 = n0base + mi*16 + lg*4;
                unsigned short* dst = base + ((size_t)(b_*NH + h)*SEQ + n0)*DH + d;
                #pragma unroll
                for (int r=0;r<4;++r) dst[r*DH] = f2bf(acc[mi][ni][r]);
            }
        }
    } else {
        // V -> fragment-major: Vf[((bh*32+kt)*2+kc)*4+dt][lane][8]
        #pragma unroll
        for (int ni=0; ni<4; ++ni){
            const int col = colB + ni*16 + ln;
            const int h  = mat*4 + ((col >> 7) & 3);
            const int d  = col & 127;
            const int dt = d >> 5;
            const int lane = (d & 31) + 32*(lg >> 1);
            const int bh = b_*NH + h;
            #pragma unroll
            for (int mi=0; mi<4; ++mi){
                const int kt = (n0base + mi*16) >> 5;
                const int kc = mi & 1;
                unsigned short* dst = Vf +
                    ((((size_t)(bh*32 + kt)*2 + kc)*4 + dt)*64 + lane)*8 + (lg&1)*4;
                bf16x4 pk;
                #pragma unroll
                for (int r=0;r<4;++r) pk[r] = (short)f2bf(acc[mi][ni][r]);
                *(bf16x4*)dst = pk;
            }
        }
    }
}

// ---------------- Kernel 2: LayerNorm + RoPE, wave-per-row (no LDS/barriers) --------
__global__ __launch_bounds__(256) void ln_rope(
    const unsigned short* __restrict__ wsqb, const unsigned short* __restrict__ wskb,
    unsigned short* __restrict__ Qb, unsigned short* __restrict__ Kb,
    const float2* __restrict__ tab,
    const float* __restrict__ g_qx, const float* __restrict__ b_qx,
    const float* __restrict__ g_kx, const float* __restrict__ b_kx,
    const float* __restrict__ g_qa, const float* __restrict__ b_qa,
    const float* __restrict__ g_ka, const float* __restrict__ b_ka)
{
    const int w0   = threadIdx.x >> 6;
    const int lane = threadIdx.x & 63;
    const int inst = blockIdx.x*4 + w0;        // 0..16383
    const int which = inst & 3;
    const int r = inst >> 2;
    const int b_ = r >> 10, n_ = r & 1023;

    const unsigned short* buf = (which & 1) ? wskb : wsqb;
    unsigned short* ob = (which & 1) ? Kb : Qb;
    const int h0 = (which >> 1) ? 4 : 0;
    const float* g; const float* bb;
    if (which==0){ g=g_qx; bb=b_qx; }
    else if (which==1){ g=g_kx; bb=b_kx; }
    else if (which==2){ g=g_qa; bb=b_qa; }
    else { g=g_ka; bb=b_ka; }

    const int hc = lane >> 4;
    const int h  = h0 + hc;
    const int d0 = (lane & 15) * 8;
    const size_t idx = ((size_t)(b_*NH + h)*SEQ + n_)*DH + d0;

    bf16x8 vin = *(const bf16x8*)(buf + idx);
    float v[8];
    float s1 = 0.f, s2 = 0.f;
    #pragma unroll
    for (int j=0;j<8;++j){
        v[j] = bf2f((unsigned short)vin[j]);
        s1 += v[j]; s2 += v[j]*v[j];
    }
    #pragma unroll
    for (int off=1; off<64; off<<=1){
        s1 += __shfl_xor(s1, off);
        s2 += __shfl_xor(s2, off);
    }
    const float mu = s1 * (1.f/512.f);
    const float var = s2 * (1.f/512.f) - mu*mu;
    const float rs = rsqrtf(var + 1e-5f);

    const int e = lane*8;
    float4 gv0 = *(const float4*)(g + e);
    float4 gv1 = *(const float4*)(g + e + 4);
    float4 bv0 = *(const float4*)(bb + e);
    float4 bv1 = *(const float4*)(bb + e + 4);
    const float gg[8]  = {gv0.x,gv0.y,gv0.z,gv0.w,gv1.x,gv1.y,gv1.z,gv1.w};
    const float bbv[8] = {bv0.x,bv0.y,bv0.z,bv0.w,bv1.x,bv1.y,bv1.z,bv1.w};

    float xn[8];
    #pragma unroll
    for (int j=0;j<8;++j) xn[j] = (v[j]-mu)*rs*gg[j] + bbv[j];

    float pr[8];
    #pragma unroll
    for (int j=0;j<8;++j) pr[j] = __shfl_xor(xn[j], 8);   // partner: d ^ 64 <=> lane ^ 8

    const bool firsthalf = (lane & 8) == 0;
    const float2* tp = tab + (n_ << 6) + (lane & 7)*8;
    const float qs = 0.08838834764831845f * 1.4426950408889634f;
    bf16x8 outv;
    #pragma unroll
    for (int j=0;j<8;++j){
        const float2 cs = tp[j];
        const float rot = firsthalf ? -pr[j] : pr[j];
        float val = xn[j]*cs.x + rot*cs.y;
        if (!(which & 1)) val *= qs;
        outv[j] = (short)f2bf(val);
    }
    *(bf16x8*)(ob + idx) = outv;
}

// ---------------- Kernel 3: 32x32 MFMA flash attention, 64 keys/phase ----------------
// 4 waves (qg, ks). K ring: 2 slots x 4 tiles (64KB) via global_load_lds, staged one
// phase ahead. V loaded global->reg from fragment-major Vf. 1 barrier/64 keys.
__global__ __launch_bounds__(256,2) void attn_mfma(
    const unsigned short* __restrict__ Qb, const unsigned short* __restrict__ Kb,
    const unsigned short* __restrict__ Vf, float* __restrict__ out)
{
    __shared__ __align__(16) unsigned short SMEM[32768];   // 64KB

    // XCD-aware remap: blocks sharing (b,h) land on one XCD
    const int nblk = blockIdx.x;
    const int jj  = nblk >> 3;
    const int bh  = (nblk & 7)*4 + (jj >> 4);
    const int q0  = (jj & 15) * 64;

    const int tid = threadIdx.x;
    const int w   = tid >> 6;
    const int qg  = w >> 1;      // q-group: rows q0+qg*32 .. +31
    const int ks  = w & 1;       // K-tile parity
    const int l   = tid & 63;
    const int lq  = l & 31;      // q column / V d-column
    const int h   = l >> 5;      // k-half within fragments
    const size_t hoff = (size_t)bh * SEQ * DH;

    bf16x8 qf[8];
    {
        const unsigned short* qp = Qb + hoff + (size_t)(q0 + qg*32 + lq)*DH + h*8;
        #pragma unroll
        for (int dc=0;dc<8;++dc) qf[dc] = *(const bf16x8*)(qp + dc*16);
    }

    f32x16 o[4];
    #pragma unroll
    for (int dt=0;dt<4;++dt)
        #pragma unroll
        for (int i=0;i<16;++i) o[dt][i] = 0.f;
    float mrun = -INFINITY, lrun = 0.f;

    const unsigned short* kg0 = Kb + hoff;
    const unsigned short* vt0 = Vf + (size_t)bh*32*4096 + l*8;   // per-tile 4096 elems

    // Stage tile group grp (tiles 4*grp .. 4*grp+3) into ring slot bb (16K shorts).
    #define STAGE_K(bb, grp) { \
        unsigned short* base_ = SMEM + (bb)*16384; \
        const unsigned short* ks_ = kg0 + (size_t)(4*(grp))*4096; \
        _Pragma("unroll") \
        for (int t_=0;t_<4;++t_) \
            _Pragma("unroll") \
            for (int i_=0;i_<2;++i_){ \
                int f_ = tid + i_*256; int r_ = f_>>4, s_ = f_&15; \
                glds16(ks_ + t_*4096 + r_*128 + ((s_ ^ (r_&7))*8), base_ + t_*4096 + f_*8); \
            } }

    #define LOADV(VF_, tile) { \
        const unsigned short* vb_ = vt0 + (size_t)(tile)*4096; \
        _Pragma("unroll") \
        for (int kc_=0;kc_<2;++kc_) \
            _Pragma("unroll") \
            for (int dt_=0;dt_<4;++dt_) \
                VF_[kc_][dt_] = *(const bf16x8*)(vb_ + (kc_*4+dt_)*512); }

    // One 32-key sub-phase: S from LDS slot, online softmax, in-register P, PV.
    #define SUB(slot, VF_) { \
        const unsigned short* kb = SMEM + cur*16384 + (slot)*4096 + lq*128; \
        f32x16 s; \
        _Pragma("unroll") \
        for (int i=0;i<16;++i) s[i] = 0.f; \
        _Pragma("unroll") \
        for (int dc=0;dc<8;++dc){ \
            bf16x8 kf = *(const bf16x8*)(kb + (((dc*2+h) ^ (lq&7))*8)); \
            s = __builtin_amdgcn_mfma_f32_32x32x16_bf16(kf, qf[dc], s, 0,0,0); \
        } \
        float mx = fmaxf(s[0], s[1]); \
        _Pragma("unroll") \
        for (int i=2;i<16;++i) mx = fmaxf(mx, s[i]); \
        mx = fmaxf(mx, __shfl_xor(mx, 32)); \
        if (__any(mx > mrun + 8.f)){ \
            const float mn = fmaxf(mrun, mx); \
            const float al = __builtin_amdgcn_exp2f(mrun - mn); \
            mrun = mn; lrun *= al; \
            _Pragma("unroll") \
            for (int dt=0;dt<4;++dt) \
                _Pragma("unroll") \
                for (int i=0;i<16;++i) o[dt][i] *= al; \
        } \
        float su = 0.f; \
        _Pragma("unroll") \
        for (int i=0;i<16;++i){ s[i] = __builtin_amdgcn_exp2f(s[i]-mrun); su += s[i]; } \
        su += __shfl_xor(su, 32); \
        lrun += su; \
        bf16x8 pf[2]; \
        _Pragma("unroll") \
        for (int kc=0; kc<2; ++kc){ \
            const int b8 = kc*8; \
            unsigned Aq, Bq, Cq, Dq; \
            asm("v_cvt_pk_bf16_f32 %0, %1, %2" : "=v"(Aq) : "v"(s[b8+0]), "v"(s[b8+1])); \
            asm("v_cvt_pk_bf16_f32 %0, %1, %2" : "=v"(Bq) : "v"(s[b8+2]), "v"(s[b8+3])); \
            asm("v_cvt_pk_bf16_f32 %0, %1, %2" : "=v"(Cq) : "v"(s[b8+4]), "v"(s[b8+5])); \
            asm("v_cvt_pk_bf16_f32 %0, %1, %2" : "=v"(Dq) : "v"(s[b8+6]), "v"(s[b8+7])); \
            asm("v_permlane32_swap_b32 %0, %1" : "+v"(Aq), "+v"(Cq)); \
            asm("v_permlane32_swap_b32 %0, %1" : "+v"(Bq), "+v"(Dq)); \
            union { unsigned u[4]; bf16x8 v; } pk; \
            pk.u[0] = Aq; pk.u[1] = Bq; pk.u[2] = Cq; pk.u[3] = Dq; \
            pf[kc] = pk.v; \
        } \
        _Pragma("unroll") \
        for (int kc=0;kc<2;++kc) \
            _Pragma("unroll") \
            for (int dt=0;dt<4;++dt) \
                o[dt] = __builtin_amdgcn_mfma_f32_32x32x16_bf16(VF_[kc][dt], pf[kc], o[dt], 0,0,0); }

    bf16x8 vf0[2][4], vf1[2][4];

    STAGE_K(0, 0);
    __syncthreads();

    int cur = 0;
    for (int ii=0; ii<8; ++ii){
        LOADV(vf0, 4*ii + ks);
        LOADV(vf1, 4*ii + 2 + ks);
        if (ii < 7) STAGE_K(cur^1, ii+1);
        SUB(ks,     vf0);
        SUB(2 + ks, vf1);
        __syncthreads();
        cur ^= 1;
    }
    #undef SUB
    #undef STAGE_K
    #undef LOADV

    // ---- epilogue: merge parity partials, transpose, store ----
    float* Lm = (float*)SMEM;            // [2 qg][2 ks][32] running max
    float* Ll = Lm + 128;                // [2 qg][2 ks][32] running sum
    Lm[(qg*2+ks)*32 + lq] = mrun;
    Ll[(qg*2+ks)*32 + lq] = lrun;
    __syncthreads();
    const float mo  = Lm[(qg*2+(ks^1))*32 + lq];
    const float lo_ = Ll[(qg*2+(ks^1))*32 + lq];
    const float mf = fmaxf(mrun, mo);
    const float a  = __builtin_amdgcn_exp2f(mrun - mf);
    const float ao = __builtin_amdgcn_exp2f(mo - mf);
    const float lf = lrun*a + lo_*ao;
    float* Ob = (float*)SMEM + 512 + qg*4160;   // [32 q][stride 129] f32
    if (ks == 1){
        #pragma unroll
        for (int dt=0;dt<4;++dt)
            #pragma unroll
            for (int r=0;r<16;++r){
                const int d = dt*32 + (r&3) + 8*(r>>2) + 4*h;
                Ob[lq*129 + d] = o[dt][r]*a;
            }
    }
    __syncthreads();
    if (ks == 0){
        const float inv = 1.0f/lf;
        #pragma unroll
        for (int dt=0;dt<4;++dt)
            #pragma unroll
            for (int r=0;r<16;++r){
                const int d = dt*32 + (r&3) + 8*(r>>2) + 4*h;
                const int idx = lq*129 + d;
                Ob[idx] = (o[dt][r]*a + Ob[idx])*inv;
            }
    }
    __syncthreads();
    const int b_ = bh >> 3, h_ = bh & 7;
    const int row = tid >> 2, quarter = tid & 3;
    const float* src = (const float*)SMEM + 512 + (row>>5)*4160 + (row&31)*129 + quarter*32;
    float* dst = out + ((size_t)(b_*SEQ) + q0 + row)*1024 + h_*128 + quarter*32;
    #pragma unroll
    for (int j=0;j<8;++j)
        *(float4*)(dst + j*4) = *(const float4*)(src + j*4);
}

extern "C" void kernel_launch(void* const* d_in, const int* in_sizes, int n_in,
                              void* d_out, int out_size, void* d_ws, size_t ws_size,
                              hipStream_t stream) {
    const float* x    = (const float*)d_in[0];
    const float* a    = (const float*)d_in[1];
    const float* Wx   = (const float*)d_in[2];
    const float* Wa   = (const float*)d_in[3];
    const float* g_qx = (const float*)d_in[4];
    const float* b_qx = (const float*)d_in[5];
    const float* g_kx = (const float*)d_in[6];
    const float* b_kx = (const float*)d_in[7];
    const float* g_qa = (const float*)d_in[8];
    const float* b_qa = (const float*)d_in[9];
    const float* g_ka = (const float*)d_in[10];
    const float* b_ka = (const float*)d_in[11];
    float* out = (float*)d_out;

    const size_t E = (size_t)BB*NH*SEQ*DH;        // 4,194,304 elements
    unsigned short* wsqb = (unsigned short*)d_ws; // 8MB bf16 pre-LN q
    unsigned short* wskb = wsqb + E;              // 8MB bf16 pre-LN k
    unsigned short* Vf   = wskb + E;              // 8MB fragment-major V
    unsigned short* region = Vf + E;
    unsigned short* Ab  = region;                 // 8MB (gemm phase)
    unsigned short* Qb  = region;                 // 8MB (attn phase, overlays Ab)
    unsigned short* Kb  = region + E;             // 8MB
    unsigned short* Bhi = region + 2*E;           // 3MB
    float2* tab = (float2*)(Bhi + (size_t)2*64*1536*8);  // 512KB

    prep_a<<<dim3(128, 2), 256, 0, stream>>>(x, a, Ab);
    prep_b<<<dim3(7, 64, 2), 256, 0, stream>>>(Wx, Wa, Bhi, tab);
    qkv_mfma<<<dim3(32, 12, 2), 256, 0, stream>>>(Ab, Bhi, wsqb, wskb, Vf);
    ln_rope<<<dim3(4096), 256, 0, stream>>>(wsqb, wskb, Qb, Kb, tab,
        g_qx, b_qx, g_kx, b_kx, g_qa, b_qa, g_ka, b_ka);
    attn_mfma<<<dim3(512), 256, 0, stream>>>(Qb, Kb, Vf, out);
}

// Round 18
// 67.250 us; speedup vs baseline: 1.0917x; 1.0489x over previous
//
#include <hip/hip_runtime.h>
#include <math.h>

typedef __attribute__((ext_vector_type(8))) short bf16x8;
typedef __attribute__((ext_vector_type(4))) short bf16x4;
typedef __attribute__((ext_vector_type(4))) float f32x4;
typedef __attribute__((ext_vector_type(16))) float f32x16;

#define BB    4
#define SEQ   1024
#define DIMV  512
#define TD    1536
#define NH    8
#define DH    128
#define MROWS (BB*SEQ)

__device__ inline unsigned short f2bf(float x){
    union { float f; unsigned u; } v; v.f = x;
    unsigned r = v.u + 0x7FFF + ((v.u >> 16) & 1);   // RNE
    return (unsigned short)(r >> 16);
}
__device__ inline float bf2f(unsigned short h){
    union { unsigned u; float f; } v; v.u = ((unsigned)h) << 16; return v.f;
}

__device__ inline void glds16(const void* g, void* l){
    __builtin_amdgcn_global_load_lds(
        (const __attribute__((address_space(1))) unsigned int*)g,
        (__attribute__((address_space(3))) unsigned int*)l,
        16, 0, 0);
}

// ---------------- Prep (fused, thin): A->bf16 granule-major | W transpose ----------
// Both branches are low-VGPR copy kernels (no trig anywhere).
__global__ __launch_bounds__(256) void prep_fused(
    const float* __restrict__ X, const float* __restrict__ A,
    unsigned short* __restrict__ Ab,
    const float* __restrict__ Wx, const float* __restrict__ Wa,
    unsigned short* __restrict__ Bhi)
{
    const int bx = blockIdx.x;
    const int t  = threadIdx.x;
    if (bx < 256){
        // A path: 128 row-groups x 2 mats; 8-lane x 256B contiguous reads
        const int mat = bx >> 7;
        const int bm  = (bx & 127) * 32;
        const float* In = mat ? A : X;
        const int rl = t >> 3;               // 0..31
        const int p8 = t & 7;                // 0..7
        const int m  = bm + rl;
        #pragma unroll
        for (int g=0; g<8; ++g){
            const int pg = g*8 + p8;
            const float* src = In + (size_t)m*DIMV + pg*8;
            float4 v0 = *(const float4*)src;
            float4 v1 = *(const float4*)(src+4);
            float v[8] = {v0.x,v0.y,v0.z,v0.w,v1.x,v1.y,v1.z,v1.w};
            bf16x8 hh;
            #pragma unroll
            for (int j=0;j<8;++j) hh[j] = (short)f2bf(v[j]);
            *(bf16x8*)(Ab + ((size_t)(mat*64 + pg)*4096 + m)*8) = hh;
        }
    } else {
        // B path: transpose W -> bf16 K-granule-major (768 blocks)
        const int bxx = bx - 256;            // 0..767
        const int mat = bxx / 384;
        const int rem = bxx - mat*384;       // 0..383
        const int pg  = rem / 6;
        const int xw  = rem - pg*6;
        const int n   = xw*256 + t;
        const float* W = mat ? Wa : Wx;
        bf16x8 h;
        #pragma unroll
        for (int j=0;j<8;++j)
            h[j] = (short)f2bf(W[(size_t)(pg*8 + j)*TD + n]);
        *(bf16x8*)(Bhi + ((size_t)(mat*64 + pg)*1536 + n)*8) = h;
    }
}

// ---------------- Kernel 1: QKV GEMM via bf16 MFMA, BK=64, 1-pass bf16 W -------------
__global__ __launch_bounds__(256,3) void qkv_mfma(
    const unsigned short* __restrict__ Ab,
    const unsigned short* __restrict__ Bhi,
    unsigned short* __restrict__ wsqb, unsigned short* __restrict__ wskb,
    unsigned short* __restrict__ Vf)
{
    __shared__ __align__(16) unsigned short sA [8192];
    __shared__ __align__(16) unsigned short sBh[8192];

    const int mat = blockIdx.z;
    const int bm  = blockIdx.x * 128;
    const int bn  = blockIdx.y * 128;
    const bool vblk = (bn >= 1024);
    const int tid = threadIdx.x;
    const int w   = tid >> 6, l = tid & 63;
    const int wr  = w >> 1,  wc = w & 1;
    const int lg  = l >> 4,  ln = l & 15;

    f32x4 acc[4][4];
    #pragma unroll
    for (int i=0;i<4;++i)
        #pragma unroll
        for (int j=0;j<4;++j){ acc[i][j][0]=0.f; acc[i][j][1]=0.f; acc[i][j][2]=0.f; acc[i][j][3]=0.f; }

    const int g0 = tid >> 7, r0 = tid & 127;
    const size_t ASTEP = (size_t)8*4096*8;     // 8 granule-panels per K-step
    const size_t BSTEP = (size_t)8*1536*8;
    const unsigned short* aP  = Ab  + ((size_t)(mat*64 + g0)*4096 + bm + r0)*8;
    const unsigned short* bPh = Bhi + ((size_t)(mat*64 + g0)*1536 + bn + r0)*8;
    const size_t AC = (size_t)2*4096*8;        // per-c offset (2 panels)
    const size_t BC = (size_t)2*1536*8;

    for (int p=0; p<8; ++p){
        #pragma unroll
        for (int c=0;c<4;++c){
            glds16(aP  + c*AC, sA  + (c*256+tid)*8);
            glds16(bPh + c*BC, sBh + (c*256+tid)*8);
        }
        aP += ASTEP; bPh += BSTEP;
        __syncthreads();

        #pragma unroll
        for (int kk=0;kk<2;++kk){
            bf16x8 av[4], bh[4];
            #pragma unroll
            for (int mi=0; mi<4; ++mi){
                const int off = ((kk*4+lg)*128 + wr*64 + mi*16 + ln)*8;
                av[mi] = *(const bf16x8*)(sA + off);
            }
            #pragma unroll
            for (int ni=0; ni<4; ++ni){
                const int off = ((kk*4+lg)*128 + wc*64 + ni*16 + ln)*8;
                bh[ni] = *(const bf16x8*)(sBh + off);
            }
            #pragma unroll
            for (int mi=0; mi<4; ++mi)
                #pragma unroll
                for (int ni=0; ni<4; ++ni)
                    acc[mi][ni] = __builtin_amdgcn_mfma_f32_16x16x32_bf16(av[mi], bh[ni], acc[mi][ni], 0,0,0);
        }
        __syncthreads();
    }

    const int b_ = bm >> 10;
    const int n0base = (bm & 1023) + wr*64;
    const int colB = bn + wc*64;
    if (!vblk){
        unsigned short* base = (colB < 512) ? wsqb : wskb;
        #pragma unroll
        for (int ni=0; ni<4; ++ni){
            const int col = colB + ni*16 + ln;
            const int h = mat*4 + ((col >> 7) & 3);
            const int d = col & 127;
            #pragma unroll
            for (int mi=0; mi<4; ++mi){
                const int n0 = n0base + mi*16 + lg*4;
                unsigned short* dst = base + ((size_t)(b_*NH + h)*SEQ + n0)*DH + d;
                #pragma unroll
                for (int r=0;r<4;++r) dst[r*DH] = f2bf(acc[mi][ni][r]);
            }
        }
    } else {
        // V -> fragment-major: Vf[((bh*32+kt)*2+kc)*4+dt][lane][8]
        #pragma unroll
        for (int ni=0; ni<4; ++ni){
            const int col = colB + ni*16 + ln;
            const int h  = mat*4 + ((col >> 7) & 3);
            const int d  = col & 127;
            const int dt = d >> 5;
            const int lane = (d & 31) + 32*(lg >> 1);
            const int bh = b_*NH + h;
            #pragma unroll
            for (int mi=0; mi<4; ++mi){
                const int kt = (n0base + mi*16) >> 5;
                const int kc = mi & 1;
                unsigned short* dst = Vf +
                    ((((size_t)(bh*32 + kt)*2 + kc)*4 + dt)*64 + lane)*8 + (lg&1)*4;
                bf16x4 pk;
                #pragma unroll
                for (int r=0;r<4;++r) pk[r] = (short)f2bf(acc[mi][ni][r]);
                *(bf16x4*)dst = pk;
            }
        }
    }
}

// ---------------- Kernel 2: LayerNorm + RoPE, wave-per-row, inline fast trig --------
__global__ __launch_bounds__(256) void ln_rope(
    const unsigned short* __restrict__ wsqb, const unsigned short* __restrict__ wskb,
    unsigned short* __restrict__ Qb, unsigned short* __restrict__ Kb,
    const float* __restrict__ g_qx, const float* __restrict__ b_qx,
    const float* __restrict__ g_kx, const float* __restrict__ b_kx,
    const float* __restrict__ g_qa, const float* __restrict__ b_qa,
    const float* __restrict__ g_ka, const float* __restrict__ b_ka)
{
    const int w0   = threadIdx.x >> 6;
    const int lane = threadIdx.x & 63;
    const int inst = blockIdx.x*4 + w0;        // 0..16383
    const int which = inst & 3;
    const int r = inst >> 2;
    const int b_ = r >> 10, n_ = r & 1023;

    const unsigned short* buf = (which & 1) ? wskb : wsqb;
    unsigned short* ob = (which & 1) ? Kb : Qb;
    const int h0 = (which >> 1) ? 4 : 0;
    const float* g; const float* bb;
    if (which==0){ g=g_qx; bb=b_qx; }
    else if (which==1){ g=g_kx; bb=b_kx; }
    else if (which==2){ g=g_qa; bb=b_qa; }
    else { g=g_ka; bb=b_ka; }

    const int hc = lane >> 4;
    const int h  = h0 + hc;
    const int d0 = (lane & 15) * 8;
    const size_t idx = ((size_t)(b_*NH + h)*SEQ + n_)*DH + d0;

    bf16x8 vin = *(const bf16x8*)(buf + idx);
    float v[8];
    float s1 = 0.f, s2 = 0.f;
    #pragma unroll
    for (int j=0;j<8;++j){
        v[j] = bf2f((unsigned short)vin[j]);
        s1 += v[j]; s2 += v[j]*v[j];
    }
    #pragma unroll
    for (int off=1; off<64; off<<=1){
        s1 += __shfl_xor(s1, off);
        s2 += __shfl_xor(s2, off);
    }
    const float mu = s1 * (1.f/512.f);
    const float var = s2 * (1.f/512.f) - mu*mu;
    const float rs = rsqrtf(var + 1e-5f);

    const int e = lane*8;
    float4 gv0 = *(const float4*)(g + e);
    float4 gv1 = *(const float4*)(g + e + 4);
    float4 bv0 = *(const float4*)(bb + e);
    float4 bv1 = *(const float4*)(bb + e + 4);
    const float gg[8]  = {gv0.x,gv0.y,gv0.z,gv0.w,gv1.x,gv1.y,gv1.z,gv1.w};
    const float bbv[8] = {bv0.x,bv0.y,bv0.z,bv0.w,bv1.x,bv1.y,bv1.z,bv1.w};

    float xn[8];
    #pragma unroll
    for (int j=0;j<8;++j) xn[j] = (v[j]-mu)*rs*gg[j] + bbv[j];

    float pr[8];
    #pragma unroll
    for (int j=0;j<8;++j) pr[j] = __shfl_xor(xn[j], 8);   // partner: d ^ 64 <=> lane ^ 8

    const bool firsthalf = (lane & 8) == 0;
    const int ddb = (lane & 7)*8;
    const float nf = (float)n_;
    const float qs = 0.08838834764831845f * 1.4426950408889634f;
    bf16x8 outv;
    #pragma unroll
    for (int j=0;j<8;++j){
        // inv = 10000^{-dd/64} via exp2; rev-reduce then fast sin/cos (arg <= 2pi)
        const float inv = __builtin_amdgcn_exp2f((float)(ddb+j) * -0.20762050593045605f);
        const float ang = nf * inv;
        float rev = ang * 0.15915494309189535f;
        rev -= floorf(rev);
        const float ar = rev * 6.2831853071795865f;
        const float sn = __sinf(ar);
        const float cs = __cosf(ar);
        const float rot = firsthalf ? -pr[j] : pr[j];
        float val = xn[j]*cs + rot*sn;
        if (!(which & 1)) val *= qs;
        outv[j] = (short)f2bf(val);
    }
    *(bf16x8*)(ob + idx) = outv;
}

// ---------------- Kernel 3: 32x32 MFMA flash attention, 64 keys/phase ----------------
// 4 waves (qg, ks). K ring: 2 slots x 4 tiles (64KB) via global_load_lds, staged one
// phase ahead. V loaded global->reg from fragment-major Vf. 1 barrier/64 keys.
__global__ __launch_bounds__(256,2) void attn_mfma(
    const unsigned short* __restrict__ Qb, const unsigned short* __restrict__ Kb,
    const unsigned short* __restrict__ Vf, float* __restrict__ out)
{
    __shared__ __align__(16) unsigned short SMEM[32768];   // 64KB

    // XCD-aware remap: blocks sharing (b,h) land on one XCD
    const int nblk = blockIdx.x;
    const int jj  = nblk >> 3;
    const int bh  = (nblk & 7)*4 + (jj >> 4);
    const int q0  = (jj & 15) * 64;

    const int tid = threadIdx.x;
    const int w   = tid >> 6;
    const int qg  = w >> 1;      // q-group: rows q0+qg*32 .. +31
    const int ks  = w & 1;       // K-tile parity
    const int l   = tid & 63;
    const int lq  = l & 31;      // q column / V d-column
    const int h   = l >> 5;      // k-half within fragments
    const size_t hoff = (size_t)bh * SEQ * DH;

    bf16x8 qf[8];
    {
        const unsigned short* qp = Qb + hoff + (size_t)(q0 + qg*32 + lq)*DH + h*8;
        #pragma unroll
        for (int dc=0;dc<8;++dc) qf[dc] = *(const bf16x8*)(qp + dc*16);
    }

    f32x16 o[4];
    #pragma unroll
    for (int dt=0;dt<4;++dt)
        #pragma unroll
        for (int i=0;i<16;++i) o[dt][i] = 0.f;
    float mrun = -INFINITY, lrun = 0.f;

    const unsigned short* kg0 = Kb + hoff;
    const unsigned short* vt0 = Vf + (size_t)bh*32*4096 + l*8;   // per-tile 4096 elems

    // Stage tile group grp (tiles 4*grp .. 4*grp+3) into ring slot bb (16K shorts).
    #define STAGE_K(bb, grp) { \
        unsigned short* base_ = SMEM + (bb)*16384; \
        const unsigned short* ks_ = kg0 + (size_t)(4*(grp))*4096; \
        _Pragma("unroll") \
        for (int t_=0;t_<4;++t_) \
            _Pragma("unroll") \
            for (int i_=0;i_<2;++i_){ \
                int f_ = tid + i_*256; int r_ = f_>>4, s_ = f_&15; \
                glds16(ks_ + t_*4096 + r_*128 + ((s_ ^ (r_&7))*8), base_ + t_*4096 + f_*8); \
            } }

    #define LOADV(VF_, tile) { \
        const unsigned short* vb_ = vt0 + (size_t)(tile)*4096; \
        _Pragma("unroll") \
        for (int kc_=0;kc_<2;++kc_) \
            _Pragma("unroll") \
            for (int dt_=0;dt_<4;++dt_) \
                VF_[kc_][dt_] = *(const bf16x8*)(vb_ + (kc_*4+dt_)*512); }

    // One 32-key sub-phase: S from LDS slot, online softmax, in-register P, PV.
    #define SUB(slot, VF_) { \
        const unsigned short* kb = SMEM + cur*16384 + (slot)*4096 + lq*128; \
        f32x16 s; \
        _Pragma("unroll") \
        for (int i=0;i<16;++i) s[i] = 0.f; \
        _Pragma("unroll") \
        for (int dc=0;dc<8;++dc){ \
            bf16x8 kf = *(const bf16x8*)(kb + (((dc*2+h) ^ (lq&7))*8)); \
            s = __builtin_amdgcn_mfma_f32_32x32x16_bf16(kf, qf[dc], s, 0,0,0); \
        } \
        float mx = fmaxf(s[0], s[1]); \
        _Pragma("unroll") \
        for (int i=2;i<16;++i) mx = fmaxf(mx, s[i]); \
        mx = fmaxf(mx, __shfl_xor(mx, 32)); \
        if (__any(mx > mrun + 8.f)){ \
            const float mn = fmaxf(mrun, mx); \
            const float al = __builtin_amdgcn_exp2f(mrun - mn); \
            mrun = mn; lrun *= al; \
            _Pragma("unroll") \
            for (int dt=0;dt<4;++dt) \
                _Pragma("unroll") \
                for (int i=0;i<16;++i) o[dt][i] *= al; \
        } \
        float su = 0.f; \
        _Pragma("unroll") \
        for (int i=0;i<16;++i){ s[i] = __builtin_amdgcn_exp2f(s[i]-mrun); su += s[i]; } \
        su += __shfl_xor(su, 32); \
        lrun += su; \
        bf16x8 pf[2]; \
        _Pragma("unroll") \
        for (int kc=0; kc<2; ++kc){ \
            const int b8 = kc*8; \
            unsigned Aq, Bq, Cq, Dq; \
            asm("v_cvt_pk_bf16_f32 %0, %1, %2" : "=v"(Aq) : "v"(s[b8+0]), "v"(s[b8+1])); \
            asm("v_cvt_pk_bf16_f32 %0, %1, %2" : "=v"(Bq) : "v"(s[b8+2]), "v"(s[b8+3])); \
            asm("v_cvt_pk_bf16_f32 %0, %1, %2" : "=v"(Cq) : "v"(s[b8+4]), "v"(s[b8+5])); \
            asm("v_cvt_pk_bf16_f32 %0, %1, %2" : "=v"(Dq) : "v"(s[b8+6]), "v"(s[b8+7])); \
            asm("v_permlane32_swap_b32 %0, %1" : "+v"(Aq), "+v"(Cq)); \
            asm("v_permlane32_swap_b32 %0, %1" : "+v"(Bq), "+v"(Dq)); \
            union { unsigned u[4]; bf16x8 v; } pk; \
            pk.u[0] = Aq; pk.u[1] = Bq; pk.u[2] = Cq; pk.u[3] = Dq; \
            pf[kc] = pk.v; \
        } \
        _Pragma("unroll") \
        for (int kc=0;kc<2;++kc) \
            _Pragma("unroll") \
            for (int dt=0;dt<4;++dt) \
                o[dt] = __builtin_amdgcn_mfma_f32_32x32x16_bf16(VF_[kc][dt], pf[kc], o[dt], 0,0,0); }

    bf16x8 vf0[2][4], vf1[2][4];

    STAGE_K(0, 0);
    __syncthreads();

    int cur = 0;
    for (int ii=0; ii<8; ++ii){
        LOADV(vf0, 4*ii + ks);
        LOADV(vf1, 4*ii + 2 + ks);
        if (ii < 7) STAGE_K(cur^1, ii+1);
        SUB(ks,     vf0);
        SUB(2 + ks, vf1);
        __syncthreads();
        cur ^= 1;
    }
    #undef SUB
    #undef STAGE_K
    #undef LOADV

    // ---- epilogue: merge parity partials, transpose, store ----
    float* Lm = (float*)SMEM;            // [2 qg][2 ks][32] running max
    float* Ll = Lm + 128;                // [2 qg][2 ks][32] running sum
    Lm[(qg*2+ks)*32 + lq] = mrun;
    Ll[(qg*2+ks)*32 + lq] = lrun;
    __syncthreads();
    const float mo  = Lm[(qg*2+(ks^1))*32 + lq];
    const float lo_ = Ll[(qg*2+(ks^1))*32 + lq];
    const float mf = fmaxf(mrun, mo);
    const float a  = __builtin_amdgcn_exp2f(mrun - mf);
    const float ao = __builtin_amdgcn_exp2f(mo - mf);
    const float lf = lrun*a + lo_*ao;
    float* Ob = (float*)SMEM + 512 + qg*4160;   // [32 q][stride 129] f32
    if (ks == 1){
        #pragma unroll
        for (int dt=0;dt<4;++dt)
            #pragma unroll
            for (int r=0;r<16;++r){
                const int d = dt*32 + (r&3) + 8*(r>>2) + 4*h;
                Ob[lq*129 + d] = o[dt][r]*a;
            }
    }
    __syncthreads();
    if (ks == 0){
        const float inv = 1.0f/lf;
        #pragma unroll
        for (int dt=0;dt<4;++dt)
            #pragma unroll
            for (int r=0;r<16;++r){
                const int d = dt*32 + (r&3) + 8*(r>>2) + 4*h;
                const int idx = lq*129 + d;
                Ob[idx] = (o[dt][r]*a + Ob[idx])*inv;
            }
    }
    __syncthreads();
    const int b_ = bh >> 3, h_ = bh & 7;
    const int row = tid >> 2, quarter = tid & 3;
    const float* src = (const float*)SMEM + 512 + (row>>5)*4160 + (row&31)*129 + quarter*32;
    float* dst = out + ((size_t)(b_*SEQ) + q0 + row)*1024 + h_*128 + quarter*32;
    #pragma unroll
    for (int j=0;j<8;++j)
        *(float4*)(dst + j*4) = *(const float4*)(src + j*4);
}

extern "C" void kernel_launch(void* const* d_in, const int* in_sizes, int n_in,
                              void* d_out, int out_size, void* d_ws, size_t ws_size,
                              hipStream_t stream) {
    const float* x    = (const float*)d_in[0];
    const float* a    = (const float*)d_in[1];
    const float* Wx   = (const float*)d_in[2];
    const float* Wa   = (const float*)d_in[3];
    const float* g_qx = (const float*)d_in[4];
    const float* b_qx = (const float*)d_in[5];
    const float* g_kx = (const float*)d_in[6];
    const float* b_kx = (const float*)d_in[7];
    const float* g_qa = (const float*)d_in[8];
    const float* b_qa = (const float*)d_in[9];
    const float* g_ka = (const float*)d_in[10];
    const float* b_ka = (const float*)d_in[11];
    float* out = (float*)d_out;

    const size_t E = (size_t)BB*NH*SEQ*DH;        // 4,194,304 elements
    unsigned short* wsqb = (unsigned short*)d_ws; // 8MB bf16 pre-LN q
    unsigned short* wskb = wsqb + E;              // 8MB bf16 pre-LN k
    unsigned short* Vf   = wskb + E;              // 8MB fragment-major V
    unsigned short* region = Vf + E;
    unsigned short* Ab  = region;                 // 8MB (gemm phase)
    unsigned short* Qb  = region;                 // 8MB (attn phase, overlays Ab)
    unsigned short* Kb  = region + E;             // 8MB
    unsigned short* Bhi = region + 2*E;           // 3MB

    prep_fused<<<dim3(1024), 256, 0, stream>>>(x, a, Ab, Wx, Wa, Bhi);
    qkv_mfma<<<dim3(32, 12, 2), 256, 0, stream>>>(Ab, Bhi, wsqb, wskb, Vf);
    ln_rope<<<dim3(4096), 256, 0, stream>>>(wsqb, wskb, Qb, Kb,
        g_qx, b_qx, g_kx, b_kx, g_qa, b_qa, g_ka, b_ka);
    attn_mfma<<<dim3(512), 256, 0, stream>>>(Qb, Kb, Vf, out);
}